// Round 4
// baseline (84.904 us; speedup 1.0000x reference)
//
#include <hip/hip_runtime.h>

#define Hdim   128
#define Anodes 512
#define Bbatch 64
#define Eedges 16384
#define AMASK  (Anodes - 1)

// ws float offsets
#define WS_CNT 0
#define WS_C   512
#define WS_PM  1024                       // f32[512][512] = 262144
#define WS_S   (1024 + 262144)            // f32[512][128]
#define WS_U   (WS_S + 65536)             // f32[512][128]
#define WS_W1T (WS_U + 65536)             // bf16[128][128] = 8192 floats
#define WS_ZBYTES ((size_t)(1024 + 262144) * 4)   // cnt + C + Pm

typedef __attribute__((ext_vector_type(8))) short short8;
typedef __attribute__((ext_vector_type(4))) float f32x4;

__device__ __forceinline__ short f2bf(float f) {
    union { float f; unsigned u; } v; v.f = f;
    unsigned r = v.u + 0x7FFFu + ((v.u >> 16) & 1u);
    return (short)(r >> 16);
}

// blocks 0..63: edge histogram Pm[s][d] += 1, cnt[d] += 1
// blocks 64..67: w1T_bf16[n][k] = bf16(w1[k][n]) into ws
__global__ __launch_bounds__(256)
void k_prep(const int* __restrict__ ei, const float* __restrict__ w1,
            float* __restrict__ ws) {
    __shared__ float t[32][129];
    const int blk = blockIdx.x;
    if (blk < 64) {
        int e = blk * 256 + threadIdx.x;
        int s = ei[e] & AMASK;
        int d = ei[Eedges + e] & AMASK;
        atomicAdd(ws + WS_PM + s * Anodes + d, 1.0f);
        atomicAdd(ws + WS_CNT + d, 1.0f);
    } else {
        short* o = (short*)(ws + WS_W1T);
        const int k0 = (blk - 64) * 32;
        for (int i = threadIdx.x; i < 32 * 128; i += 256) {
            int r = i >> 7, c = i & 127;
            t[r][c] = w1[(k0 + r) * Hdim + c];
        }
        __syncthreads();
        const int n  = threadIdx.x >> 1;
        const int j0 = (threadIdx.x & 1) * 16;
        short tmp[16];
        #pragma unroll
        for (int j = 0; j < 16; ++j) tmp[j] = f2bf(t[j0 + j][n]);
        short8* dst = (short8*)(o + n * Hdim + k0 + j0);
        dst[0] = *(short8*)(tmp);
        dst[1] = *(short8*)(tmp + 8);
    }
}

// Block a: W[a,h] = wfc[a*H+h]/max(cnt,1);  S[a,k] = sum_h w2[k*H+h]*W[a,h]
// Also accumulates C = sum_{a:cnt>0} sum_h b2[h]*wfc[a*H+h]
__global__ void k_S(const float* __restrict__ w2, const float* __restrict__ wfc,
                    const float* __restrict__ b2, float* __restrict__ ws) {
    __shared__ float Wrow[Hdim];
    __shared__ float red[2];
    const int a = blockIdx.x;
    const int h = threadIdx.x;
    const float c   = ws[WS_CNT + a];
    const float inv = 1.0f / fmaxf(c, 1.0f);
    const float wf  = wfc[a * Hdim + h];
    Wrow[h] = wf * inv;
    float cb = (c > 0.f) ? b2[h] * wf : 0.f;
    for (int off = 32; off; off >>= 1) cb += __shfl_down(cb, off, 64);
    if ((h & 63) == 0) red[h >> 6] = cb;
    __syncthreads();
    if (h == 0 && (red[0] + red[1]) != 0.f) atomicAdd(ws + WS_C, red[0] + red[1]);
    float s = 0.f;
    #pragma unroll 8
    for (int hh = 0; hh < Hdim; ++hh) s += w2[h * Hdim + hh] * Wrow[hh];
    ws[WS_S + a * Hdim + h] = s;
}

// U = Pm @ S  (64 blocks x 8 rows); block 0 also writes out[b] = bfc + C
__global__ __launch_bounds__(256)
void k_U2(const float* __restrict__ bfc, float* __restrict__ ws,
          float* __restrict__ out) {
    __shared__ float pmL[8][Anodes];   // 16 KB
    const int tid = threadIdx.x;
    const int s0  = blockIdx.x * 8;
    if (blockIdx.x == 0 && tid < Bbatch) out[tid] = bfc[0] + ws[WS_C];

    const float* Pm = ws + WS_PM + (size_t)s0 * Anodes;
    for (int i = tid; i < 8 * Anodes; i += 256)
        pmL[i >> 9][i & (Anodes - 1)] = Pm[i];
    __syncthreads();

    const int k  = tid & 127;
    const int sr = (tid >> 7) * 4;   // rows sr..sr+3
    const float* S = ws + WS_S;
    float u0 = 0.f, u1 = 0.f, u2 = 0.f, u3 = 0.f;
    for (int d = 0; d < Anodes; ++d) {
        float p0 = pmL[sr + 0][d], p1 = pmL[sr + 1][d];
        float p2 = pmL[sr + 2][d], p3 = pmL[sr + 3][d];
        if ((p0 + p1 + p2 + p3) != 0.f) {       // counts >= 0: exact
            float sv = S[d * Hdim + k];
            u0 += p0 * sv; u1 += p1 * sv; u2 += p2 * sv; u3 += p3 * sv;
        }
    }
    float* U = ws + WS_U + (size_t)(s0 + sr) * Hdim + k;
    U[0] = u0; U[Hdim] = u1; U[2 * Hdim] = u2; U[3 * Hdim] = u3;
}

// MFMA: per block 64 rows; out[b] += sum_rows relu(x_row @ w1 + b1) . U[a,:]
__global__ __launch_bounds__(256)
void k_main(const float* __restrict__ x, const float* __restrict__ b1,
            const float* __restrict__ ws, float* __restrict__ out) {
    __shared__ short w1s[Hdim * Hdim];   // swizzled bf16 [n][k], 32 KB
    __shared__ float red[4];

    const int tid  = threadIdx.x;
    const int row0 = blockIdx.x * 64;
    const int b    = blockIdx.x >> 3;
    const int a0   = (blockIdx.x & 7) * 64;

    {
        const short8* gsrc = (const short8*)(ws + WS_W1T);
        for (int i = tid; i < 2048; i += 256) {
            short8 v = gsrc[i];
            int n = i >> 4;
            int byte = (i * 16) ^ ((n & 7) << 4);
            *(short8*)((char*)w1s + byte) = v;
        }
    }
    __syncthreads();

    const int w = tid >> 6;
    const int l = tid & 63;
    const int c = l & 15;
    const int g = l >> 4;

    const float* xrow = x + (size_t)(row0 + w * 16 + c) * Hdim;

    f32x4 acc[8];
    #pragma unroll
    for (int n = 0; n < 8; ++n) acc[n] = (f32x4){0.f, 0.f, 0.f, 0.f};

    #pragma unroll
    for (int ks = 0; ks < 4; ++ks) {
        const int k0 = ks * 32;
        float4 a_lo = *(const float4*)(xrow + k0 + 8 * g);
        float4 a_hi = *(const float4*)(xrow + k0 + 8 * g + 4);
        short8 a;
        a[0] = f2bf(a_lo.x); a[1] = f2bf(a_lo.y); a[2] = f2bf(a_lo.z); a[3] = f2bf(a_lo.w);
        a[4] = f2bf(a_hi.x); a[5] = f2bf(a_hi.y); a[6] = f2bf(a_hi.z); a[7] = f2bf(a_hi.w);
        #pragma unroll
        for (int n = 0; n < 8; ++n) {
            int byte = (((n * 16 + c) << 8) + ((k0 + 8 * g) << 1)) ^ ((c & 7) << 4);
            short8 bf = *(short8*)((char*)w1s + byte);
            acc[n] = __builtin_amdgcn_mfma_f32_16x16x32_bf16(a, bf, acc[n], 0, 0, 0);
        }
    }

    float part = 0.f;
    const float* U = ws + WS_U;
    #pragma unroll
    for (int n = 0; n < 8; ++n) {
        const int colg = n * 16 + c;
        const float bv = b1[colg];
        #pragma unroll
        for (int r = 0; r < 4; ++r) {
            const int arow = a0 + w * 16 + g * 4 + r;
            float z = acc[n][r] + bv;
            part += fmaxf(z, 0.f) * U[arow * Hdim + colg];
        }
    }
    #pragma unroll
    for (int off = 32; off; off >>= 1) part += __shfl_down(part, off, 64);
    if (l == 0) red[w] = part;
    __syncthreads();
    if (tid == 0) atomicAdd(out + b, red[0] + red[1] + red[2] + red[3]);
}

extern "C" void kernel_launch(void* const* d_in, const int* in_sizes, int n_in,
                              void* d_out, int out_size, void* d_ws, size_t ws_size,
                              hipStream_t stream) {
    const float* x   = (const float*)d_in[0];
    // d_in[1] = pos (unused)
    const int*   ei  = (const int*)d_in[2];
    const float* w1  = (const float*)d_in[3];
    const float* b1  = (const float*)d_in[4];
    const float* w2  = (const float*)d_in[5];
    const float* b2  = (const float*)d_in[6];
    const float* wfc = (const float*)d_in[7];
    const float* bfc = (const float*)d_in[8];
    float* out = (float*)d_out;
    float* ws  = (float*)d_ws;

    hipMemsetAsync(ws, 0, WS_ZBYTES, stream);                     // cnt + C + Pm
    hipLaunchKernelGGL(k_prep, dim3(68),     dim3(256),  0, stream, ei, w1, ws);
    hipLaunchKernelGGL(k_S,    dim3(Anodes), dim3(Hdim), 0, stream, w2, wfc, b2, ws);
    hipLaunchKernelGGL(k_U2,   dim3(64),     dim3(256),  0, stream, bfc, ws, out);
    hipLaunchKernelGGL(k_main, dim3(512),    dim3(256),  0, stream, x, b1, ws, out);
}

// Round 5
// 42.096 us; speedup vs baseline: 2.0169x; 2.0169x over previous
//
#include <hip/hip_runtime.h>

#define Hdim   128
#define Anodes 512
#define Bbatch 64
#define Eedges 16384
#define AMASK  (Anodes - 1)

// ws float offsets
#define WS_CNT 0
#define WS_C   512
#define WS_PM  1024                       // f32[512][512]
#define WS_G   (1024 + 262144)            // f32[512][128]
#define WS_U   (WS_G + 65536)             // f32[512][128]
#define WS_W1T (WS_U + 65536)             // bf16[128][128] (as 8192 f32)
#define WS_W2B (WS_W1T + 8192)            // bf16[128][128] (as 8192 f32)
#define WS_ZBYTES ((size_t)(1024 + 262144) * 4)   // cnt + C + Pm

typedef __attribute__((ext_vector_type(8))) short short8;
typedef __attribute__((ext_vector_type(4))) float f32x4;

__device__ __forceinline__ short f2bf(float f) {
    union { float f; unsigned u; } v; v.f = f;
    unsigned r = v.u + 0x7FFFu + ((v.u >> 16) & 1u);
    return (short)(r >> 16);
}

// blocks 0..63: edge histogram Pm[s][d] += 1, cnt[d] += 1
// blocks 64..67: w1T_bf16[n][k] = bf16(w1[k][n])
// blocks 68..69: w2b_bf16[k][h] = bf16(w2[k][h])  (straight copy)
__global__ __launch_bounds__(256)
void k_prep(const int* __restrict__ ei, const float* __restrict__ w1,
            const float* __restrict__ w2, float* __restrict__ ws) {
    __shared__ float t[32][129];
    const int blk = blockIdx.x;
    if (blk < 64) {
        int e = blk * 256 + threadIdx.x;
        int s = ei[e] & AMASK;
        int d = ei[Eedges + e] & AMASK;
        atomicAdd(ws + WS_PM + s * Anodes + d, 1.0f);
        atomicAdd(ws + WS_CNT + d, 1.0f);
    } else if (blk < 68) {
        short* o = (short*)(ws + WS_W1T);
        const int k0 = (blk - 64) * 32;
        for (int i = threadIdx.x; i < 32 * 128; i += 256) {
            int r = i >> 7, c = i & 127;
            t[r][c] = w1[(k0 + r) * Hdim + c];
        }
        __syncthreads();
        const int n  = threadIdx.x >> 1;
        const int j0 = (threadIdx.x & 1) * 16;
        short tmp[16];
        #pragma unroll
        for (int j = 0; j < 16; ++j) tmp[j] = f2bf(t[j0 + j][n]);
        short8* dst = (short8*)(o + n * Hdim + k0 + j0);
        dst[0] = *(short8*)(tmp);
        dst[1] = *(short8*)(tmp + 8);
    } else {
        const float2* src = (const float2*)w2;
        unsigned* dst = (unsigned*)(ws + WS_W2B);
        for (int i = (blk - 68) * 256 + threadIdx.x; i < 8192; i += 512) {
            float2 v = src[i];
            unsigned lo = (unsigned short)f2bf(v.x);
            unsigned hi = (unsigned short)f2bf(v.y);
            dst[i] = lo | (hi << 16);
        }
    }
}

// blocks 0..511: G[s,:] = sum_d Pm[s][d]/max(cnt_d,1) * wfc[d,:]
// blocks 512..519: C partials = sum_{d:cnt>0} sum_h b2[h]*wfc[d,h]
__global__ __launch_bounds__(256)
void k_G(const float* __restrict__ wfc, const float* __restrict__ b2,
         float* __restrict__ ws) {
    __shared__ unsigned short dlist[Anodes];
    __shared__ float plist[Anodes];
    __shared__ float gred[Hdim];
    __shared__ float red[4];
    __shared__ int nz;
    const int tid = threadIdx.x;
    const int s = blockIdx.x;
    if (s < Anodes) {
        if (tid == 0) nz = 0;
        __syncthreads();
        float2 pv = ((const float2*)(ws + WS_PM + (size_t)s * Anodes))[tid];
        #pragma unroll
        for (int q = 0; q < 2; ++q) {
            float p = q ? pv.y : pv.x;
            if (p != 0.f) {
                int d = 2 * tid + q;
                int slot = atomicAdd(&nz, 1);
                dlist[slot] = (unsigned short)d;
                plist[slot] = p / fmaxf(ws[WS_CNT + d], 1.0f);
            }
        }
        __syncthreads();
        const int n = nz;
        const int k = tid & 127;
        const int half = tid >> 7;
        float g = 0.f;
        for (int i = half; i < n; i += 2)
            g += plist[i] * wfc[(size_t)dlist[i] * Hdim + k];
        if (half) gred[k] = g;
        __syncthreads();
        if (!half) ws[WS_G + (size_t)s * Hdim + k] = g + gred[k];
    } else {
        const int d0 = (s - Anodes) * 64;
        const int h  = tid & 127;
        const int dp = tid >> 7;
        float cp = 0.f;
        for (int dl = dp; dl < 64; dl += 2) {
            int d = d0 + dl;
            if (ws[WS_CNT + d] > 0.f) cp += b2[h] * wfc[(size_t)d * Hdim + h];
        }
        #pragma unroll
        for (int off = 32; off; off >>= 1) cp += __shfl_down(cp, off, 64);
        if ((tid & 63) == 0) red[tid >> 6] = cp;
        __syncthreads();
        if (tid == 0) {
            float c = red[0] + red[1] + red[2] + red[3];
            if (c != 0.f) atomicAdd(ws + WS_C, c);
        }
    }
}

// U = G @ w2^T via MFMA (8 blocks x 64 rows); block 0 inits out[b] = bfc + C
__global__ __launch_bounds__(256)
void k_U3(const float* __restrict__ bfc, float* __restrict__ ws,
          float* __restrict__ out) {
    const int tid = threadIdx.x;
    if (blockIdx.x == 0 && tid < Bbatch) out[tid] = bfc[0] + ws[WS_C];
    const int w = tid >> 6, l = tid & 63, c = l & 15, g = l >> 4;
    const int s0 = blockIdx.x * 64 + w * 16;
    const float* grow = ws + WS_G + (size_t)(s0 + c) * Hdim;
    const short* w2b  = (const short*)(ws + WS_W2B);

    f32x4 acc[8];
    #pragma unroll
    for (int n = 0; n < 8; ++n) acc[n] = (f32x4){0.f, 0.f, 0.f, 0.f};

    #pragma unroll
    for (int ks = 0; ks < 4; ++ks) {
        const int k0 = ks * 32 + 8 * g;
        float4 alo = *(const float4*)(grow + k0);
        float4 ahi = *(const float4*)(grow + k0 + 4);
        short8 a;
        a[0] = f2bf(alo.x); a[1] = f2bf(alo.y); a[2] = f2bf(alo.z); a[3] = f2bf(alo.w);
        a[4] = f2bf(ahi.x); a[5] = f2bf(ahi.y); a[6] = f2bf(ahi.z); a[7] = f2bf(ahi.w);
        #pragma unroll
        for (int n = 0; n < 8; ++n) {
            short8 bf = *(const short8*)(w2b + (n * 16 + c) * Hdim + k0);
            acc[n] = __builtin_amdgcn_mfma_f32_16x16x32_bf16(a, bf, acc[n], 0, 0, 0);
        }
    }
    float* U = ws + WS_U;
    #pragma unroll
    for (int n = 0; n < 8; ++n)
        #pragma unroll
        for (int r = 0; r < 4; ++r)
            U[(size_t)(s0 + g * 4 + r) * Hdim + n * 16 + c] = acc[n][r];
}

// MFMA: per block 64 rows; out[b] += sum_rows relu(x_row @ w1 + b1) . U[a,:]
__global__ __launch_bounds__(256)
void k_main(const float* __restrict__ x, const float* __restrict__ b1,
            const float* __restrict__ ws, float* __restrict__ out) {
    __shared__ short w1s[Hdim * Hdim];   // swizzled bf16 [n][k], 32 KB
    __shared__ float red[4];

    const int tid  = threadIdx.x;
    const int row0 = blockIdx.x * 64;
    const int b    = blockIdx.x >> 3;
    const int a0   = (blockIdx.x & 7) * 64;

    {
        const short8* gsrc = (const short8*)(ws + WS_W1T);
        for (int i = tid; i < 2048; i += 256) {
            short8 v = gsrc[i];
            int n = i >> 4;
            int byte = (i * 16) ^ ((n & 7) << 4);
            *(short8*)((char*)w1s + byte) = v;
        }
    }
    __syncthreads();

    const int w = tid >> 6;
    const int l = tid & 63;
    const int c = l & 15;
    const int g = l >> 4;

    const float* xrow = x + (size_t)(row0 + w * 16 + c) * Hdim;

    f32x4 acc[8];
    #pragma unroll
    for (int n = 0; n < 8; ++n) acc[n] = (f32x4){0.f, 0.f, 0.f, 0.f};

    #pragma unroll
    for (int ks = 0; ks < 4; ++ks) {
        const int k0 = ks * 32;
        float4 a_lo = *(const float4*)(xrow + k0 + 8 * g);
        float4 a_hi = *(const float4*)(xrow + k0 + 8 * g + 4);
        short8 a;
        a[0] = f2bf(a_lo.x); a[1] = f2bf(a_lo.y); a[2] = f2bf(a_lo.z); a[3] = f2bf(a_lo.w);
        a[4] = f2bf(a_hi.x); a[5] = f2bf(a_hi.y); a[6] = f2bf(a_hi.z); a[7] = f2bf(a_hi.w);
        #pragma unroll
        for (int n = 0; n < 8; ++n) {
            int byte = (((n * 16 + c) << 8) + ((k0 + 8 * g) << 1)) ^ ((c & 7) << 4);
            short8 bf = *(short8*)((char*)w1s + byte);
            acc[n] = __builtin_amdgcn_mfma_f32_16x16x32_bf16(a, bf, acc[n], 0, 0, 0);
        }
    }

    float part = 0.f;
    const float* U = ws + WS_U;
    #pragma unroll
    for (int n = 0; n < 8; ++n) {
        const int colg = n * 16 + c;
        const float bv = b1[colg];
        #pragma unroll
        for (int r = 0; r < 4; ++r) {
            const int arow = a0 + w * 16 + g * 4 + r;
            float z = acc[n][r] + bv;
            part += fmaxf(z, 0.f) * U[arow * Hdim + colg];
        }
    }
    #pragma unroll
    for (int off = 32; off; off >>= 1) part += __shfl_down(part, off, 64);
    if (l == 0) red[w] = part;
    __syncthreads();
    if (tid == 0) atomicAdd(out + b, red[0] + red[1] + red[2] + red[3]);
}

extern "C" void kernel_launch(void* const* d_in, const int* in_sizes, int n_in,
                              void* d_out, int out_size, void* d_ws, size_t ws_size,
                              hipStream_t stream) {
    const float* x   = (const float*)d_in[0];
    // d_in[1] = pos (unused)
    const int*   ei  = (const int*)d_in[2];
    const float* w1  = (const float*)d_in[3];
    const float* b1  = (const float*)d_in[4];
    const float* w2  = (const float*)d_in[5];
    const float* b2  = (const float*)d_in[6];
    const float* wfc = (const float*)d_in[7];
    const float* bfc = (const float*)d_in[8];
    float* out = (float*)d_out;
    float* ws  = (float*)d_ws;

    hipMemsetAsync(ws, 0, WS_ZBYTES, stream);                     // cnt + C + Pm
    hipLaunchKernelGGL(k_prep, dim3(70),  dim3(256), 0, stream, ei, w1, w2, ws);
    hipLaunchKernelGGL(k_G,    dim3(520), dim3(256), 0, stream, wfc, b2, ws);
    hipLaunchKernelGGL(k_U3,   dim3(8),   dim3(256), 0, stream, bfc, ws, out);
    hipLaunchKernelGGL(k_main, dim3(512), dim3(256), 0, stream, x, b1, ws, out);
}